// Round 1
// baseline (67.674 us; speedup 1.0000x reference)
//
#include <hip/hip_runtime.h>
#include <hip/hip_bf16.h>

typedef __attribute__((ext_vector_type(4))) float f32x4;
typedef __attribute__((ext_vector_type(4))) unsigned int u32x4;
typedef __attribute__((ext_vector_type(8))) __bf16 bf16x8;

namespace {
constexpr int T_ = 4096;
constexpr int K_ = 2048;
constexpr int N_ = 1024;
constexpr int E_ = 8;
constexpr int BM = 128, BN = 128, BK = 32;
constexpr int NK = K_ / BK;     // 64 K-steps
constexpr int LSTR = BK + 8;    // 40 ushorts = 80B row stride -> conflict-free b128 frag reads
}

__device__ __forceinline__ unsigned int pk2(float a, float b) {
    union { __hip_bfloat162 h; unsigned int u; } c;
    c.h = __float22bfloat162_rn(make_float2(a, b));   // v_cvt_pk_bf16_f32
    return c.u;
}

__device__ __forceinline__ u32x4 cvt8(f32x4 a, f32x4 b) {
    u32x4 r;
    r.x = pk2(a.x, a.y);
    r.y = pk2(a.z, a.w);
    r.z = pk2(b.x, b.y);
    r.w = pk2(b.z, b.w);
    return r;
}

__global__ __launch_bounds__(256, 1) void gg_bf16_kernel(
        const float* __restrict__ x, const float* __restrict__ w,
        const int* __restrict__ offs, float* __restrict__ y) {
    // Double-buffered bf16 tiles, padded to kill ds_read_b128 bank conflicts.
    __shared__ __align__(16) unsigned short As[2][BM * LSTR];  // 20 KB
    __shared__ __align__(16) unsigned short Bs[2][BN * LSTR];  // 20 KB

    const int tid = threadIdx.x;
    const int lane = tid & 63;
    const int wid = tid >> 6;
    const int wr = wid >> 1, wc = wid & 1;  // 2x2 wave grid, 64x64 out per wave

    // XCD-aware decode: HW assigns XCD = blockIdx % 8; make b&7 the block-row
    // group (== expert for equal split) so each expert's 32 tiles share an XCD L2.
    const int b = blockIdx.x;                 // 0..255
    const int xcd = b & 7;
    const int inner = b >> 3;                 // 0..31
    const int by = xcd * 4 + (inner >> 3);    // 0..31
    const int bx = inner & 7;                 // 0..7
    const int brow = by * BM;
    const int bcol = bx * BN;

    // Staging map: 256 threads x (2 rows x 8 floats) per operand per K-step.
    const int srow = tid >> 2;                // 0..63
    const int scol = (tid & 3) * 8;           // 0,8,16,24 (floats)
    const float* aB0 = x + (size_t)(brow + srow) * K_ + scol;
    const float* aB1 = aB0 + (size_t)64 * K_;
    const int ldsO0 = srow * LSTR + scol;
    const int ldsO1 = (srow + 64) * LSTR + scol;

    // MFMA fragment read offsets (A and B identical NT layout):
    // lane holds row/col = lane&15, k = 8*(lane>>4)..+7
    const int frow = lane & 15;
    const int fk = (lane >> 4) * 8;
    const int aF = (wr * 64 + frow) * LSTR + fk;
    const int bF = (wc * 64 + frow) * LSTR + fk;

#define LOADT(t)                                                      \
    do {                                                              \
        const float* _a0 = aB0 + (t) * BK;                            \
        const float* _a1 = aB1 + (t) * BK;                            \
        const float* _b0 = bB0 + (t) * BK;                            \
        const float* _b1 = bB1 + (t) * BK;                            \
        ra0 = *(const f32x4*)_a0; ra1 = *(const f32x4*)(_a0 + 4);     \
        ra2 = *(const f32x4*)_a1; ra3 = *(const f32x4*)(_a1 + 4);     \
        rb0 = *(const f32x4*)_b0; rb1 = *(const f32x4*)(_b0 + 4);     \
        rb2 = *(const f32x4*)_b1; rb3 = *(const f32x4*)(_b1 + 4);     \
    } while (0)

#define STORET(buf)                                                   \
    do {                                                              \
        *(u32x4*)&As[buf][ldsO0] = cvt8(ra0, ra1);                    \
        *(u32x4*)&As[buf][ldsO1] = cvt8(ra2, ra3);                    \
        *(u32x4*)&Bs[buf][ldsO0] = cvt8(rb0, rb1);                    \
        *(u32x4*)&Bs[buf][ldsO1] = cvt8(rb2, rb3);                    \
    } while (0)

    for (int e = 0; e < E_; ++e) {
        const int s = (e == 0) ? 0 : offs[e - 1];
        const int en = offs[e];
        // Block-uniform test: does expert e's token range touch this row tile?
        if (en <= brow || s >= brow + BM) continue;

        const float* bB0 = w + ((size_t)e * N_ + bcol + srow) * K_ + scol;
        const float* bB1 = bB0 + (size_t)64 * K_;

        f32x4 ra0, ra1, ra2, ra3, rb0, rb1, rb2, rb3;
        LOADT(0);
        STORET(0);
        __syncthreads();

        f32x4 acc[4][4];
#pragma unroll
        for (int m = 0; m < 4; ++m)
#pragma unroll
            for (int n = 0; n < 4; ++n)
                acc[m][n] = f32x4{0.0f, 0.0f, 0.0f, 0.0f};

        for (int t = 0; t < NK; ++t) {
            const int cur = t & 1;
            if (t + 1 < NK) LOADT(t + 1);   // issue next-tile global loads early
            bf16x8 af[4], bg[4];
#pragma unroll
            for (int m = 0; m < 4; ++m)
                af[m] = *(const bf16x8*)&As[cur][aF + m * 16 * LSTR];
#pragma unroll
            for (int n = 0; n < 4; ++n)
                bg[n] = *(const bf16x8*)&Bs[cur][bF + n * 16 * LSTR];
#pragma unroll
            for (int m = 0; m < 4; ++m)
#pragma unroll
                for (int n = 0; n < 4; ++n)
                    acc[m][n] = __builtin_amdgcn_mfma_f32_16x16x32_bf16(
                        af[m], bg[n], acc[m][n], 0, 0, 0);
            if (t + 1 < NK) STORET(cur ^ 1);  // cvt + write other buffer (no hazard)
            __syncthreads();                   // one barrier per K-step
        }

        // C/D layout (m89-verified): col = lane&15, row = (lane>>4)*4 + reg
        const int cb = bcol + wc * 64 + frow;
#pragma unroll
        for (int m = 0; m < 4; ++m) {
            const int r0 = brow + wr * 64 + m * 16 + (lane >> 4) * 4;
#pragma unroll
            for (int r = 0; r < 4; ++r) {
                const int row = r0 + r;
                if (row < s || row >= en) continue;  // ragged-boundary mask
                float* yp = y + (size_t)row * N_ + cb;
#pragma unroll
                for (int n = 0; n < 4; ++n) yp[n * 16] = acc[m][n][r];
            }
        }
        __syncthreads();  // uniform; protects LDS reuse across expert passes
    }
#undef LOADT
#undef STORET
}

extern "C" void kernel_launch(void* const* d_in, const int* in_sizes, int n_in,
                              void* d_out, int out_size, void* d_ws, size_t ws_size,
                              hipStream_t stream) {
    const float* x = (const float*)d_in[0];
    const float* w = (const float*)d_in[1];
    const int* offs = (const int*)d_in[2];
    float* y = (float*)d_out;
    const int grid = (T_ / BM) * (N_ / BN);  // 256 blocks = 1 per CU
    gg_bf16_kernel<<<dim3(grid), dim3(256), 0, stream>>>(x, w, offs, y);
}

// Round 3
// 49.839 us; speedup vs baseline: 1.3579x; 1.3579x over previous
//
#include <hip/hip_runtime.h>
#include <hip/hip_bf16.h>

typedef __attribute__((ext_vector_type(4))) float f32x4;
typedef __attribute__((ext_vector_type(4))) unsigned int u32x4;
typedef __attribute__((ext_vector_type(8))) __bf16 bf16x8;

namespace {
constexpr int T_ = 4096;
constexpr int K_ = 2048;
constexpr int N_ = 1024;
constexpr int E_ = 8;
constexpr int BM = 128, BN = 128, BK = 32;
constexpr int KSPLIT = 2;
constexpr int KHALF = K_ / KSPLIT;        // 1024
constexpr int NKS = KHALF / BK;           // 32 K-steps per block
constexpr int LSTR = BK + 8;              // 40 ushorts = 80B stride
constexpr size_t PART_ELEMS = (size_t)T_ * N_;   // 4M floats per partial
}

__device__ __forceinline__ unsigned int pk2(float a, float b) {
    union { __hip_bfloat162 h; unsigned int u; } c;
    c.h = __float22bfloat162_rn(make_float2(a, b));   // v_cvt_pk_bf16_f32
    return c.u;
}

__device__ __forceinline__ u32x4 cvt8(f32x4 a, f32x4 b) {
    u32x4 r;
    r.x = pk2(a.x, a.y);
    r.y = pk2(a.z, a.w);
    r.z = pk2(b.x, b.y);
    r.w = pk2(b.z, b.w);
    return r;
}

// ATOMIC=0: plain stores of split-K partials into part plane [ks]; reduce sums.
// ATOMIC=1: atomicAdd directly into y (fallback when ws too small; y pre-zeroed).
template <int ATOMIC>
__global__ __launch_bounds__(256, 2) void gg_bf16_kernel(
        const float* __restrict__ x, const float* __restrict__ w,
        const int* __restrict__ offs, float* __restrict__ out) {
    __shared__ __align__(16) unsigned short As[2][BM * LSTR];  // 20 KB
    __shared__ __align__(16) unsigned short Bs[2][BN * LSTR];  // 20 KB

    const int tid = threadIdx.x;
    const int lane = tid & 63;
    const int wid = tid >> 6;
    const int wr = wid >> 1, wc = wid & 1;  // 2x2 wave grid, 64x64 out per wave

    // 512 blocks. xcd = b&7 (HW round-robin); each XCD owns 4 row-tiles of ONE
    // expert (both K-halves) so its L2 sees a single 8MB weight panel.
    const int b = blockIdx.x;
    const int xcd = b & 7;
    const int inner = b >> 3;                 // 0..63
    const int ks = inner >> 5;                // 0..1  K-split half
    const int rem = inner & 31;
    const int by = xcd * 4 + (rem >> 3);      // 0..31
    const int bx = rem & 7;                   // 0..7
    const int brow = by * BM;
    const int bcol = bx * BN;
    const int k0 = ks * KHALF;                // float offset into K

    // *** the round-2 bug: partial plane must be selected by ks ***
    float* outp = ATOMIC ? out : (out + (size_t)ks * PART_ELEMS);

    // Staging: 256 threads x (2 rows x 8 floats) per operand per K-step.
    const int srow = tid >> 2;                // 0..63
    const int scol = (tid & 3) * 8;           // 0,8,16,24 (floats)
    const float* aB0 = x + (size_t)(brow + srow) * K_ + k0 + scol;
    const float* aB1 = aB0 + (size_t)64 * K_;
    const int ldsO0 = srow * LSTR + scol;
    const int ldsO1 = (srow + 64) * LSTR + scol;

    // MFMA fragment offsets: lane holds row/col = lane&15, k = 8*(lane>>4)..+7
    const int frow = lane & 15;
    const int fk = (lane >> 4) * 8;
    const int aF = (wr * 64 + frow) * LSTR + fk;
    const int bF = (wc * 64 + frow) * LSTR + fk;

#define LOADT(t)                                                      \
    do {                                                              \
        const float* _a0 = aB0 + (t) * BK;                            \
        const float* _a1 = aB1 + (t) * BK;                            \
        const float* _b0 = bB0 + (t) * BK;                            \
        const float* _b1 = bB1 + (t) * BK;                            \
        ra0 = *(const f32x4*)_a0; ra1 = *(const f32x4*)(_a0 + 4);     \
        ra2 = *(const f32x4*)_a1; ra3 = *(const f32x4*)(_a1 + 4);     \
        rb0 = *(const f32x4*)_b0; rb1 = *(const f32x4*)(_b0 + 4);     \
        rb2 = *(const f32x4*)_b1; rb3 = *(const f32x4*)(_b1 + 4);     \
    } while (0)

#define STORET(buf)                                                   \
    do {                                                              \
        *(u32x4*)&As[buf][ldsO0] = cvt8(ra0, ra1);                    \
        *(u32x4*)&As[buf][ldsO1] = cvt8(ra2, ra3);                    \
        *(u32x4*)&Bs[buf][ldsO0] = cvt8(rb0, rb1);                    \
        *(u32x4*)&Bs[buf][ldsO1] = cvt8(rb2, rb3);                    \
    } while (0)

    for (int e = 0; e < E_; ++e) {
        const int s = (e == 0) ? 0 : offs[e - 1];
        const int en = offs[e];
        if (en <= brow || s >= brow + BM) continue;  // block-uniform

        const float* bB0 = w + ((size_t)e * N_ + bcol + srow) * K_ + k0 + scol;
        const float* bB1 = bB0 + (size_t)64 * K_;

        f32x4 ra0, ra1, ra2, ra3, rb0, rb1, rb2, rb3;
        LOADT(0);
        STORET(0);
        __syncthreads();

        f32x4 acc[4][4];
#pragma unroll
        for (int m = 0; m < 4; ++m)
#pragma unroll
            for (int n = 0; n < 4; ++n)
                acc[m][n] = f32x4{0.0f, 0.0f, 0.0f, 0.0f};

        for (int t = 0; t < NKS; ++t) {
            const int cur = t & 1;
            if (t + 1 < NKS) LOADT(t + 1);   // issue next-tile global loads early
            bf16x8 af[4], bg[4];
#pragma unroll
            for (int m = 0; m < 4; ++m)
                af[m] = *(const bf16x8*)&As[cur][aF + m * 16 * LSTR];
#pragma unroll
            for (int n = 0; n < 4; ++n)
                bg[n] = *(const bf16x8*)&Bs[cur][bF + n * 16 * LSTR];
#pragma unroll
            for (int m = 0; m < 4; ++m)
#pragma unroll
                for (int n = 0; n < 4; ++n)
                    acc[m][n] = __builtin_amdgcn_mfma_f32_16x16x32_bf16(
                        af[m], bg[n], acc[m][n], 0, 0, 0);
            if (t + 1 < NKS) STORET(cur ^ 1);
            __syncthreads();
        }

        // C/D layout: col = lane&15, row = (lane>>4)*4 + reg
        const int cb = bcol + wc * 64 + frow;
#pragma unroll
        for (int m = 0; m < 4; ++m) {
            const int r0 = brow + wr * 64 + m * 16 + (lane >> 4) * 4;
#pragma unroll
            for (int r = 0; r < 4; ++r) {
                const int row = r0 + r;
                if (row < s || row >= en) continue;  // ragged-boundary mask
                float* yp = outp + (size_t)row * N_ + cb;
#pragma unroll
                for (int n = 0; n < 4; ++n) {
                    if (ATOMIC) atomicAdd(&yp[n * 16], acc[m][n][r]);
                    else        yp[n * 16] = acc[m][n][r];
                }
            }
        }
        __syncthreads();  // uniform; protects LDS reuse across expert passes
    }
#undef LOADT
#undef STORET
}

__global__ __launch_bounds__(256) void gg_reduce_kernel(
        const float* __restrict__ part, float* __restrict__ y) {
    const size_t i = (size_t)blockIdx.x * blockDim.x + threadIdx.x;  // f32x4 idx
    const f32x4 a = ((const f32x4*)part)[i];
    const f32x4 b = ((const f32x4*)(part + PART_ELEMS))[i];
    ((f32x4*)y)[i] = a + b;
}

extern "C" void kernel_launch(void* const* d_in, const int* in_sizes, int n_in,
                              void* d_out, int out_size, void* d_ws, size_t ws_size,
                              hipStream_t stream) {
    const float* x = (const float*)d_in[0];
    const float* w = (const float*)d_in[1];
    const int* offs = (const int*)d_in[2];
    float* y = (float*)d_out;
    const int grid = (T_ / BM) * (N_ / BN) * KSPLIT;  // 512 blocks = 2 per CU

    if (ws_size >= KSPLIT * PART_ELEMS * sizeof(float)) {
        float* part = (float*)d_ws;
        // ks=0 -> part[0..4M), ks=1 -> part[4M..8M); every element of both
        // planes is written (each row belongs to exactly one expert).
        gg_bf16_kernel<0><<<dim3(grid), dim3(256), 0, stream>>>(x, w, offs, part);
        gg_reduce_kernel<<<dim3((int)(PART_ELEMS / 4 / 256)), dim3(256), 0, stream>>>(part, y);
    } else {
        hipMemsetAsync(d_out, 0, PART_ELEMS * sizeof(float), stream);
        gg_bf16_kernel<1><<<dim3(grid), dim3(256), 0, stream>>>(x, w, offs, y);
    }
}